// Round 2
// baseline (674.119 us; speedup 1.0000x reference)
//
#include <hip/hip_runtime.h>

#define HDIM 16
#define SCAN_BLK 1024  // elements per scan block (256 threads x 4)

// ---------------------------------------------------------------------------
// cnt[dst] += 1 for every edge (int atomics)
// ---------------------------------------------------------------------------
__global__ void count_kernel(const int* __restrict__ dst, int* __restrict__ cnt, int E) {
    int e = blockIdx.x * blockDim.x + threadIdx.x;
    if (e < E) atomicAdd(&cnt[dst[e]], 1);
}

// dinv[i] = rsqrt(cnt[i] + 1)   (+1 = self-loop)
__global__ void dinv_kernel(const int* __restrict__ cnt, float* __restrict__ dinv, int n) {
    int i = blockIdx.x * blockDim.x + threadIdx.x;
    if (i < n) dinv[i] = rsqrtf((float)cnt[i] + 1.0f);
}

// ---------------------------------------------------------------------------
// exclusive scan of cnt[] (in place) -> row starts; bsum gets per-block totals
// ---------------------------------------------------------------------------
__global__ void scan1_kernel(int* __restrict__ data, int* __restrict__ bsum, int n) {
    __shared__ int sh[256];
    int base = blockIdx.x * SCAN_BLK;
    int off = base + threadIdx.x * 4;
    int vals[4];
    int local = 0;
#pragma unroll
    for (int k = 0; k < 4; ++k) {
        int v = (off + k < n) ? data[off + k] : 0;
        vals[k] = v;
        local += v;
    }
    sh[threadIdx.x] = local;
    __syncthreads();
#pragma unroll
    for (int d = 1; d < 256; d <<= 1) {
        int t = (threadIdx.x >= d) ? sh[threadIdx.x - d] : 0;
        __syncthreads();
        sh[threadIdx.x] += t;
        __syncthreads();
    }
    int run = (threadIdx.x == 0) ? 0 : sh[threadIdx.x - 1];
#pragma unroll
    for (int k = 0; k < 4; ++k) {
        if (off + k < n) data[off + k] = run;
        run += vals[k];
    }
    if (threadIdx.x == 0) bsum[blockIdx.x] = sh[255];
}

__global__ void scan2_kernel(int* __restrict__ bsum, int nb) {
    __shared__ int sh[512];
    int v = (threadIdx.x < nb) ? bsum[threadIdx.x] : 0;
    sh[threadIdx.x] = v;
    __syncthreads();
    for (int d = 1; d < 512; d <<= 1) {
        int t = (threadIdx.x >= d) ? sh[threadIdx.x - d] : 0;
        __syncthreads();
        sh[threadIdx.x] += t;
        __syncthreads();
    }
    int excl = (threadIdx.x == 0) ? 0 : sh[threadIdx.x - 1];
    if (threadIdx.x < nb) bsum[threadIdx.x] = excl;
}

__global__ void scan3_kernel(int* __restrict__ data, const int* __restrict__ bsum, int n) {
    int i = blockIdx.x * blockDim.x + threadIdx.x;
    if (i < n) data[i] += bsum[i / SCAN_BLK];
}

// ---------------------------------------------------------------------------
// CSR fill: pos = rowptr[d]++ ; col[pos] = src.  Afterwards rowptr[d] = row end.
// ---------------------------------------------------------------------------
__global__ void fill_kernel(const int* __restrict__ src, const int* __restrict__ dst,
                            int* __restrict__ rowptr, int* __restrict__ col, int E) {
    int e = blockIdx.x * blockDim.x + threadIdx.x;
    if (e < E) {
        int d = dst[e];
        int pos = atomicAdd(&rowptr[d], 1);
        col[pos] = src[e];
    }
}

// ---------------------------------------------------------------------------
// Y[n,16] = X[n,K] @ W[K,16]   — W staged in LDS, one thread per row
// ---------------------------------------------------------------------------
template <int K>
__global__ void gemm_kernel(const float* __restrict__ X, const float* __restrict__ W,
                            float* __restrict__ Y, int n) {
    __shared__ float Wl[K * HDIM];
    for (int t = threadIdx.x; t < K * HDIM; t += blockDim.x) Wl[t] = W[t];
    __syncthreads();

    int row = blockIdx.x * blockDim.x + threadIdx.x;
    int stride = gridDim.x * blockDim.x;
    for (; row < n; row += stride) {
        float acc[HDIM];
#pragma unroll
        for (int j = 0; j < HDIM; ++j) acc[j] = 0.0f;
        const float* xr = X + (size_t)row * K;
#pragma unroll
        for (int k = 0; k < K; ++k) {
            float xv = xr[k];
#pragma unroll
            for (int j = 0; j < HDIM; ++j)
                acc[j] = fmaf(xv, Wl[k * HDIM + j], acc[j]);
        }
        float4* yo = (float4*)(Y + (size_t)row * HDIM);
        yo[0] = make_float4(acc[0], acc[1], acc[2], acc[3]);
        yo[1] = make_float4(acc[4], acc[5], acc[6], acc[7]);
        yo[2] = make_float4(acc[8], acc[9], acc[10], acc[11]);
        yo[3] = make_float4(acc[12], acc[13], acc[14], acc[15]);
    }
}

// ---------------------------------------------------------------------------
// Gather-aggregate: 16 threads per row (one per feature).
//   acc_j   = sum_{s in N(i)} dinv[s] * h[s,j]
//   r_j     = relu( dinv[i]*(acc_j + dinv[i]*h[i,j]) + bias_j )
//   FUSE_W2 ? out[i,:] = r @ W2 (via 16-lane shuffles) : out[i,j] = r_j
// rowptr holds row ENDS after fill; start = rowptr[i-1] (0 for i==0).
// ---------------------------------------------------------------------------
template <bool FUSE_W2>
__global__ void gather_kernel(const int* __restrict__ col, const int* __restrict__ rowptr,
                              const float* __restrict__ h, const float* __restrict__ dinv,
                              const float* __restrict__ bias, const float* __restrict__ W2,
                              float* __restrict__ out, int n) {
    __shared__ float W2l[HDIM * HDIM];
    if constexpr (FUSE_W2) {
        for (int t = threadIdx.x; t < HDIM * HDIM; t += blockDim.x) W2l[t] = W2[t];
        __syncthreads();
    }
    int idx = blockIdx.x * blockDim.x + threadIdx.x;
    if (idx >= n * HDIM) return;
    int i = idx >> 4;
    int j = idx & 15;
    int start = (i == 0) ? 0 : rowptr[i - 1];
    int end = rowptr[i];
    float acc = 0.0f;
    for (int k = start; k < end; ++k) {
        int s = col[k];
        acc = fmaf(dinv[s], h[(size_t)s * HDIM + j], acc);
    }
    float di = dinv[i];
    float r = fmaxf(fmaf(di, acc + di * h[(size_t)i * HDIM + j], bias[j]), 0.0f);
    if constexpr (FUSE_W2) {
        float o = 0.0f;
#pragma unroll
        for (int jj = 0; jj < HDIM; ++jj) {
            float rv = __shfl(r, jj, HDIM);  // within the row's 16-lane group
            o = fmaf(rv, W2l[jj * HDIM + j], o);
        }
        out[idx] = o;
    } else {
        out[idx] = r;
    }
}

extern "C" void kernel_launch(void* const* d_in, const int* in_sizes, int n_in,
                              void* d_out, int out_size, void* d_ws, size_t ws_size,
                              hipStream_t stream) {
    const float* x  = (const float*)d_in[0];   // [n, 54]
    const int*   ei = (const int*)d_in[1];     // [2, E] (int32)
    const float* W1 = (const float*)d_in[2];   // [54, 16]
    const float* b1 = (const float*)d_in[3];   // [16]
    const float* W2 = (const float*)d_in[4];   // [16, 16]
    const float* b2 = (const float*)d_in[5];   // [16]
    float* out = (float*)d_out;

    const int E = in_sizes[1] / 2;             // 3,200,000
    const int n = in_sizes[0] / 54;            // 100,000
    const int* src = ei;
    const int* dst = ei + E;

    char* w = (char*)d_ws;
    float* dinv   = (float*)w;                 w += (size_t)n * 4;
    float* hA     = (float*)w;                 w += (size_t)n * HDIM * 4;
    float* hB     = (float*)w;                 w += (size_t)n * HDIM * 4;
    int*   rowptr = (int*)w;                   w += (size_t)n * 4;
    int*   bsum   = (int*)w;                   w += 512 * 4;
    int*   col    = (int*)w;                   // E ints

    const int B = 256;
    const int nb = (n + SCAN_BLK - 1) / SCAN_BLK;  // scan blocks (98)

    // --- build degree + CSR (shared by both layers) ---
    hipMemsetAsync(rowptr, 0, (size_t)n * sizeof(int), stream);
    count_kernel<<<(E + B - 1) / B, B, 0, stream>>>(dst, rowptr, E);
    dinv_kernel<<<(n + B - 1) / B, B, 0, stream>>>(rowptr, dinv, n);
    scan1_kernel<<<nb, 256, 0, stream>>>(rowptr, bsum, n);
    scan2_kernel<<<1, 512, 0, stream>>>(bsum, nb);
    scan3_kernel<<<(n + B - 1) / B, B, 0, stream>>>(rowptr, bsum, n);
    fill_kernel<<<(E + B - 1) / B, B, 0, stream>>>(src, dst, rowptr, col, E);

    // --- layer 1 transform ---
    gemm_kernel<54><<<1024, B, 0, stream>>>(x, W1, hA, n);

    // --- layer 1 aggregate + relu + fused @W2  ->  hB ---
    gather_kernel<true><<<(n * HDIM + B - 1) / B, B, 0, stream>>>(
        col, rowptr, hA, dinv, b1, W2, hB, n);

    // --- layer 2 aggregate + bias + relu -> out ---
    gather_kernel<false><<<(n * HDIM + B - 1) / B, B, 0, stream>>>(
        col, rowptr, hB, dinv, b2, nullptr, out, n);
}